// Round 6
// baseline (153.485 us; speedup 1.0000x reference)
//
#include <hip/hip_runtime.h>

// CritiGraph fused loss, MI355X (gfx950). Round 6: two-kernel split.
//
//  * voc_emb is DEAD in the reference (eu_val[:,64:] never used) -> never read.
//  * pack15: apos = (abs<<15)|(v<0). XOR of two packed gives abs-xor in bits 15..30 and
//    sign product in bit 0; (y + 0x8000) = (absxor+1)<<15 | sgn exactly, so
//    cos*scale = (clz(y+0x8000)-1)*(scale/16), sign applied via (y<<31)^bits.
//  * loss_dyn_dyn = kl + lse_s(ct) - sum_s p_eu*ct ; loss_dyn_sta = lse_v(20ct) - 20ct[tar].
//  * log2 domain throughout (LOG2E folded); staged tables hold E = exp2(base).
//  * R6 structure: crit_prep builds a 14.5KB per-t blob in d_ws (packed locs + E tables +
//    cnc + dotbase + kl + tar); crit_main (2 blocks/t, 4 blocks/CU) loads the blob from
//    L2 and runs the pure-VALU hot loop. Decouples the latency-bound prep chain from the
//    throughput-bound pair loop (R3/R4/R5 all plateaued ~35us with monolithic blocks).

#define Tn   512
#define NC   65
#define TPd  8
#define NTn  64
#define KV   128
#define Dn   256
#define OUT1 (Tn * NC * TPd)
#define WSTRIDE 4096              // ints per t in ws (16KB)
#define BLOBI   3712              // ints copied (928 int4)
#define BLOB4   928

#define LOG2E 1.44269504088896340736f
#define LN2   0.69314718055994530942f
#define ADYN (0.125f * LOG2E * 0.0625f)
#define ASTA (2.5f  * LOG2E * 0.0625f)
#define ARAW 0.0625f

__device__ __forceinline__ float exp2_fast(float x) {
#if __has_builtin(__builtin_amdgcn_exp2f)
    return __builtin_amdgcn_exp2f(x);
#else
    return exp2f(x);
#endif
}
__device__ __forceinline__ float asf(int v) { return __int_as_float(v); }
__device__ __forceinline__ int   asi(float v) { return __float_as_int(v); }

__device__ __forceinline__ int pack15(int v) {
    int a = (v < 0) ? -v : v;
    return (a << 15) | (int)(((unsigned)v) >> 31);
}
__device__ __forceinline__ float cos15(int y, float A) {
    int   x = y + 0x8000;
    float c = fmaf((float)__clz(x), A, -A);
    return asf(asi(c) ^ (y << 31));
}
// element index: 2 consecutive s for same p contiguous (b128 = 2 elems)
__device__ __forceinline__ int eidx(int s, int p) {
    return ((s >> 1) * TPd + p) * 2 + (s & 1);
}

// ---------------- prep: per-t blob into ws ----------------
// blob ints: [0..1023] dyn2 {apos, E_bf16<<16|peu_bf16}; [1024..3071] sta2 {apos, E f32};
//            [3072..3591] cnc packed; [3600..3607] dotbase; [3608] kl; [3609] tar.
__global__ __launch_bounds__(256, 4) void crit_prep(
    const int*   __restrict__ cur_tar,
    const int*   __restrict__ cnc_loc,
    const int*   __restrict__ sta_loc,
    const int*   __restrict__ ttn_loc,
    const int*   __restrict__ voc_loc,
    const float* __restrict__ sta_emb,
    const float* __restrict__ ttn_emb,
    int*         __restrict__ ws)
{
    __shared__ int4  blob4[BLOB4];
    int*   blob = (int*)blob4;
    int2*  dynT = (int2*)blob;            // [512]
    int2*  staT = (int2*)(blob + 1024);   // [1024]
    int*   cncT = blob + 3072;            // [520]
    float* dotb = (float*)(blob + 3600);
    __shared__ float s_b2d[NTn * TPd];
    __shared__ float s_csum[192];
    __shared__ float s_eu[NTn];
    __shared__ float s_peu[NTn];
    __shared__ int   s_staloc[TPd];

    const int t   = blockIdx.x;
    const int tid = threadIdx.x;

    if (tid < TPd) s_staloc[tid] = pack15(sta_loc[t * TPd + tid]);
    if (tid == 0)  blob[3609] = cur_tar[t];
    for (int i = tid; i < NC * TPd; i += 256)
        cncT[i] = pack15(cnc_loc[t * NC * TPd + i]);
    __syncthreads();

    // pos tables (apos + raw cos_sp), csum via 8-lane shuffles; eu dot
    const int mysta = s_staloc[tid & 7];
    float mysp[6];
    #pragma unroll
    for (int k = 0; k < 6; ++k) {
        int i = tid + 256 * k;
        int s = i >> 3, p = i & 7;
        int v = (s < NTn) ? ttn_loc[t * NTn * TPd + i]
                          : voc_loc[t * KV * TPd + (i - NTn * TPd)];
        int packed = pack15(v);
        float c = cos15(packed ^ mysta, ARAW);
        mysp[k] = c;
        if (s < NTn) dynT[eidx(s, p)].x = packed;
        else         staT[eidx(s - NTn, p)].x = packed;
        float v8 = c;
        v8 += __shfl_xor(v8, 1);
        v8 += __shfl_xor(v8, 2);
        v8 += __shfl_xor(v8, 4);
        if (p == 0) s_csum[s] = v8;
    }
    {   // eu: 4 threads/row, 16 independent float4 loads each
        const int r = tid >> 2, q = tid & 3;
        const float4* A = (const float4*)(sta_emb + (size_t)t * Dn);
        const float4* B = (const float4*)(ttn_emb + ((size_t)t * NTn + r) * Dn);
        float acc = 0.f;
        #pragma unroll
        for (int k = 0; k < 16; ++k) {
            float4 a = A[k * 4 + q];
            float4 b = B[k * 4 + q];
            acc += a.x * b.x + a.y * b.y + a.z * b.z + a.w * b.w;
        }
        acc += __shfl_xor(acc, 1);
        acc += __shfl_xor(acc, 2);
        if (q == 0) s_eu[r] = acc;                     // 20*TEMP = 1.0
    }
    __syncthreads();

    // E tables (exp2 of log2-domain base); softmax over eu (wave 0)
    #pragma unroll
    for (int k = 0; k < 6; ++k) {
        int i = tid + 256 * k;
        int s = i >> 3, p = i & 7;
        if (s < NTn) {
            float b2 = (s_csum[s] - mysp[k]) * (0.125f * LOG2E);
            int   e  = eidx(s, p);
            dynT[e].y = asi(exp2_fast(b2));            // temp: E as f32
            s_b2d[e]  = b2;
        } else {
            float b2 = (s_csum[s] - mysp[k]) * (2.5f * LOG2E);
            staT[eidx(s - NTn, p)].y = asi(exp2_fast(b2));
        }
    }
    if (tid < 64) {
        float e  = s_eu[tid];
        float mx = e;
        #pragma unroll
        for (int m = 1; m < 64; m <<= 1) mx = fmaxf(mx, __shfl_xor(mx, m));
        float ex = __expf(e - mx);
        float z  = ex;
        #pragma unroll
        for (int m = 1; m < 64; m <<= 1) z += __shfl_xor(z, m);
        float pe = ex / z;
        s_peu[tid] = pe;
        float kls = pe * ((e - mx) - __logf(z));
        #pragma unroll
        for (int m = 1; m < 64; m <<= 1) kls += __shfl_xor(kls, m);
        if (tid == 0) blob[3608] = asi(kls);
    }
    __syncthreads();

    // pack {E bf16 | peu bf16}; dotbase[p] = sum_s peu[s]*b2d[s,p]
    #pragma unroll
    for (int k = 0; k < 2; ++k) {
        int i = tid + 256 * k;
        int s = (((i >> 4) << 1) | (i & 1));
        int Eb = dynT[i].y;
        int Pb = asi(s_peu[s]);
        dynT[i].y = (int)((((unsigned)Eb + 0x8000u) & 0xFFFF0000u) |
                          (((unsigned)Pb + 0x8000u) >> 16));
    }
    if (tid < 64) {
        int g = tid & 7, j = tid >> 3;
        float a = 0.f;
        #pragma unroll
        for (int k = 0; k < 8; ++k) {
            int s = 8 * j + k;
            a = fmaf(s_peu[s], s_b2d[eidx(s, g)], a);
        }
        #pragma unroll
        for (int m = 8; m < 64; m <<= 1) a += __shfl_xor(a, m);
        if (tid < TPd) dotb[g] = a;
    }
    __syncthreads();

    int4* dst = (int4*)(ws + (size_t)t * WSTRIDE);
    for (int i = tid; i < BLOB4; i += 256) dst[i] = blob4[i];
}

// ---------------- main: hot pair loop ----------------
__global__ __launch_bounds__(256, 4) void crit_main(
    const int* __restrict__ ws,
    float*     __restrict__ out)
{
    __shared__ int4 blob4[BLOB4];
    int* blob = (int*)blob4;

    const int bx  = blockIdx.x;
    const int t   = bx >> 1;
    const int h   = bx & 1;
    const int tid = threadIdx.x;

    const int4* src = (const int4*)(ws + (size_t)t * WSTRIDE);
    for (int i = tid; i < BLOB4; i += 256) blob4[i] = src[i];
    __syncthreads();

    const int4*  dyn4 = blob4;                       // [j*8+p] = dyn elems s=2j,2j+1
    const int4*  sta4 = blob4 + 256;                 // [j*8+p] = sta elems v=2j,2j+1
    const int2*  staT = (const int2*)(blob + 1024);
    const int*   cncT = blob + 3072;
    const float* dotb = (const float*)(blob + 3600);
    const float  kl   = asf(blob[3608]);
    const int    tar  = blob[3609];

    const int   p    = tid & 7;
    const int   acnc = cncT[h * 256 + tid];          // pair c = h*32 + (tid>>3)
    const float dtb  = dotb[p];

    float sum = 0.f, dot = 0.f;
    #pragma unroll 8
    for (int j = 0; j < NTn / 2; ++j) {
        int4 q = dyn4[j * TPd + p];
        {
            int   y  = q.x ^ acnc;
            float cc = cos15(y, ADYN);
            sum = fmaf(asf(q.y & (int)0xFFFF0000), exp2_fast(cc), sum);
            dot = fmaf(asf(q.y << 16), cc, dot);
        }
        {
            int   y  = q.z ^ acnc;
            float cc = cos15(y, ADYN);
            sum = fmaf(asf(q.w & (int)0xFFFF0000), exp2_fast(cc), sum);
            dot = fmaf(asf(q.w << 16), cc, dot);
        }
    }
    float s2 = 0.f;
    #pragma unroll 8
    for (int j = 0; j < KV / 2; ++j) {
        int4 q = sta4[j * TPd + p];
        s2 = fmaf(asf(q.y), exp2_fast(cos15(q.x ^ acnc, ASTA)), s2);
        s2 = fmaf(asf(q.w), exp2_fast(cos15(q.z ^ acnc, ASTA)), s2);
    }
    {
        int2  tq  = staT[eidx(tar, p)];
        float b2t = __log2f(asf(tq.y));
        float cct = cos15(tq.x ^ acnc, ASTA);
        float* od = out + (size_t)t * NC * TPd;
        float* os = out + OUT1 + (size_t)t * NC * TPd;
        od[h * 256 + tid] = kl + LN2 * (__log2f(sum) - (dtb + dot));
        os[h * 256 + tid] = LN2 * (__log2f(s2) - (b2t + cct));
    }

    // tail (c = 64, p = 0..7): h==1 blocks, 2 pairs/wave, 32-lane s-split
    if (h == 1) {
        const int w    = tid >> 6;
        const int lane = tid & 63;
        const int half = lane >> 5;
        const int sub  = lane & 31;
        const int pt   = 2 * w + half;
        const int acw  = cncT[512 + pt];
        const int2* dynT = (const int2*)blob;
        float sumd = 0.f, dotd = 0.f, sums = 0.f;
        #pragma unroll
        for (int k = 0; k < 2; ++k) {
            int2  q  = dynT[eidx(sub + 32 * k, pt)];
            int   y  = q.x ^ acw;
            float cc = cos15(y, ADYN);
            sumd = fmaf(asf(q.y & (int)0xFFFF0000), exp2_fast(cc), sumd);
            dotd = fmaf(asf(q.y << 16), cc, dotd);
        }
        #pragma unroll
        for (int k = 0; k < 4; ++k) {
            int2 q = staT[eidx(sub + 32 * k, pt)];
            sums = fmaf(asf(q.y), exp2_fast(cos15(q.x ^ acw, ASTA)), sums);
        }
        #pragma unroll
        for (int m = 1; m < 32; m <<= 1) {
            sumd += __shfl_xor(sumd, m);
            dotd += __shfl_xor(dotd, m);
            sums += __shfl_xor(sums, m);
        }
        if (sub == 0) {
            int2  tq  = staT[eidx(tar, pt)];
            float b2t = __log2f(asf(tq.y));
            float cct = cos15(tq.x ^ acw, ASTA);
            out[(size_t)t * NC * TPd + 512 + pt] =
                kl + LN2 * (__log2f(sumd) - (dotb[pt] + dotd));
            out[OUT1 + (size_t)t * NC * TPd + 512 + pt] =
                LN2 * (__log2f(sums) - (b2t + cct));
        }
    }
}

extern "C" void kernel_launch(void* const* d_in, const int* in_sizes, int n_in,
                              void* d_out, int out_size, void* d_ws, size_t ws_size,
                              hipStream_t stream) {
    (void)in_sizes; (void)n_in; (void)ws_size; (void)out_size;
    const int*   cur_tar = (const int*)  d_in[0];
    const int*   cnc_loc = (const int*)  d_in[1];
    const int*   sta_loc = (const int*)  d_in[2];
    const int*   ttn_loc = (const int*)  d_in[3];
    const int*   voc_loc = (const int*)  d_in[4];
    const float* sta_emb = (const float*)d_in[5];
    const float* ttn_emb = (const float*)d_in[6];
    // d_in[7] (voc_emb) intentionally unused: it only feeds eu_val[:,64:], discarded.
    int* ws = (int*)d_ws;   // uses 512*16KB = 8.4MB of the scratch
    crit_prep<<<Tn, 256, 0, stream>>>(cur_tar, cnc_loc, sta_loc, ttn_loc,
                                      voc_loc, sta_emb, ttn_emb, ws);
    crit_main<<<Tn * 2, 256, 0, stream>>>(ws, (float*)d_out);
}

// Round 7
// 130.445 us; speedup vs baseline: 1.1766x; 1.1766x over previous
//
#include <hip/hip_runtime.h>

// CritiGraph fused loss, MI355X (gfx950). Round 7: prefix-pyramid aggregation.
//
//  * voc_emb is DEAD in the reference -> never read.
//  * cos_similarity depends ONLY on (highest differing bit of abs-xor, sign product).
//    For each (t,p): bucket the 64 dyn / 128 sta keys by top-6 abs bits; build a dense
//    binary pyramid (levels 1..6) of subtree sums split by sign(v), channels:
//    dynE = exp2(base2_dyn), dynP = p_eu, staE = exp2(base2_sta).
//    Per pair (c,p): level L sibling of c's prefix path contributes with e = 17-L
//    (cos = (L-1)/16), via compile-time constants T±; keys sharing c's top-6 prefix
//    (avg ~1.5) are evaluated exactly per-element (incl. the +1-carry cases).
//    ~150 VALU + ~24 DS per pair vs ~1920 + 96 for per-element evaluation.
//  * pack15: apos = (abs<<15)|(v<0); y = k^c gives sign product in bit0, abs-xor in
//    bits 15..30; (y + 0x8000) = (absxor+1)<<15 + low-junk (carry-safe), so
//    clz gives e exactly. Dyn keys stuff s into bits 1..6 (carry-safe, bucket-safe).
//  * loss_dyn_dyn = kl + lse_s(ct) - sum_s p_eu*ct ; loss_dyn_sta = lse_v(20ct)-20ct[tar].
//  * log2 domain throughout (LOG2E folded).

#define Tn   512
#define NC   65
#define TPd  8
#define NTn  64
#define KV   128
#define Dn   256
#define OUT1 (Tn * NC * TPd)

#define LOG2E 1.44269504088896340736f
#define LN2   0.69314718055994530942f
#define ADYN (0.125f * LOG2E * 0.0625f)
#define ASTA (2.5f  * LOG2E * 0.0625f)
#define ARAW 0.0625f

#define PYR_P 378   // float2 per p: [dynE 126][dynP 126][staE 126]
#define OFF_P 126
#define OFF_S 252

__device__ __forceinline__ float exp2_fast(float x) {
#if __has_builtin(__builtin_amdgcn_exp2f)
    return __builtin_amdgcn_exp2f(x);
#else
    return exp2f(x);
#endif
}
__device__ __forceinline__ float asf(int v) { return __int_as_float(v); }
__device__ __forceinline__ int   asi(float v) { return __float_as_int(v); }
__device__ __forceinline__ int pack15(int v) {
    int a = (v < 0) ? -v : v;
    return (a << 15) | (int)(((unsigned)v) >> 31);
}
__device__ __forceinline__ float cos15(int y, float A) {
    int   x = (int)((unsigned)y + 0x8000u);
    float c = fmaf((float)__clz(x), A, -A);
    return asf(asi(c) ^ (y << 31));
}

__global__ __launch_bounds__(512, 4) void critigraph_kernel(
    const int*   __restrict__ cur_tar,
    const int*   __restrict__ cnc_loc,
    const int*   __restrict__ sta_loc,
    const int*   __restrict__ ttn_loc,
    const int*   __restrict__ voc_loc,
    const float* __restrict__ sta_emb,
    const float* __restrict__ ttn_emb,
    float*       __restrict__ out)
{
    __shared__ float2 s_pyr[TPd * PYR_P];   // 24192 B, no zeroing needed (all written)
    __shared__ int2   s_dynS[NTn * TPd];    // bucket-sorted {key|s<<1, E f32}
    __shared__ int2   s_staS[KV * TPd];     // bucket-sorted {key, E f32}
    __shared__ int    s_hist[16 * 64];      // histogram -> cursors
    __shared__ int    s_starts[16 * 65];    // global slice starts per (seg,bucket)
    __shared__ int    s_cnc[NC * TPd];
    __shared__ float  s_b2d[NTn * TPd];     // log2-domain dyn base (dotbase only)
    __shared__ float  s_peu[NTn];
    __shared__ float  s_eu[NTn];
    __shared__ float  s_tarE[TPd];
    __shared__ int    s_tarK[TPd];
    __shared__ float  s_dotb[TPd];
    __shared__ float  s_kl;

    const int t   = blockIdx.x;
    const int tid = threadIdx.x;
    const int p   = tid & 7;
    const int tar = cur_tar[t];

    // ---- P0: zero hist, stage cnc ----
    s_hist[tid] = 0;
    s_hist[tid + 512] = 0;
    s_cnc[tid] = pack15(cnc_loc[t * NC * TPd + tid]);
    if (tid < 8) s_cnc[512 + tid] = pack15(cnc_loc[t * NC * TPd + 512 + tid]);
    const int mysta = pack15(sta_loc[t * TPd + p]);
    __syncthreads();

    // ---- P1: staging. 1 dyn + 2 sta elements/thread: keys, E, b2d, hist, target ----
    int   keyv[3];
    float Ev[3];
    #pragma unroll
    for (int k = 0; k < 3; ++k) {
        int i = tid + 512 * k;
        int s = i >> 3;
        int v = (s < NTn) ? ttn_loc[t * NTn * TPd + i]
                          : voc_loc[t * KV * TPd + (i - NTn * TPd)];
        int packed = pack15(v);
        float c = cos15(packed ^ mysta, ARAW);      // raw cos_sp
        float v8 = c;                               // csum over the 8-lane p-group
        v8 += __shfl_xor(v8, 1);
        v8 += __shfl_xor(v8, 2);
        v8 += __shfl_xor(v8, 4);
        if (s < NTn) {
            float b2 = (v8 - c) * (0.125f * LOG2E);
            s_b2d[i] = b2;
            Ev[k]    = exp2_fast(b2);
            keyv[k]  = packed | (s << 1);           // stuff s into bits 1..6
            atomicAdd(&s_hist[p * 64 + ((packed >> 25) & 63)], 1);
        } else {
            float b2 = (v8 - c) * (2.5f * LOG2E);
            Ev[k]    = exp2_fast(b2);
            keyv[k]  = packed;
            atomicAdd(&s_hist[(8 + p) * 64 + ((packed >> 25) & 63)], 1);
            if (s - NTn == tar) { s_tarK[p] = packed; s_tarE[p] = Ev[k]; }
        }
    }
    __syncthreads();

    // ---- P2: per-segment exclusive scan (64 buckets); hist becomes cursors ----
    {
        const int lane = tid & 63;
        #pragma unroll
        for (int rnd = 0; rnd < 2; ++rnd) {
            int seg = (tid >> 6) + rnd * 8;
            int v   = s_hist[seg * 64 + lane];
            int inc = v;
            #pragma unroll
            for (int off = 1; off < 64; off <<= 1) {
                int u = __shfl_up(inc, off);
                if (lane >= off) inc += u;
            }
            int base = (seg < 8) ? (seg * 64) : ((seg - 8) * 128);
            int excl = base + inc - v;
            s_starts[seg * 65 + lane] = excl;
            if (lane == 63) s_starts[seg * 65 + 64] = base + inc;
            s_hist[seg * 64 + lane] = excl;         // cursor
        }
    }
    __syncthreads();

    // ---- P3: scatter into bucket-sorted arrays; eu dot (loads overlap atomics) ----
    {
        const int r = tid >> 3, q = tid & 7;
        const float4* A4 = (const float4*)(sta_emb + (size_t)t * Dn);
        const float4* B4 = (const float4*)(ttn_emb + ((size_t)t * NTn + r) * Dn);
        float4 av[8], bv[8];
        #pragma unroll
        for (int k = 0; k < 8; ++k) { av[k] = A4[k * 8 + q]; bv[k] = B4[k * 8 + q]; }

        int bk = (keyv[0] >> 25) & 63;
        int ix = atomicAdd(&s_hist[p * 64 + bk], 1);
        s_dynS[ix] = make_int2(keyv[0], asi(Ev[0]));
        bk = (keyv[1] >> 25) & 63;
        ix = atomicAdd(&s_hist[(8 + p) * 64 + bk], 1);
        s_staS[ix] = make_int2(keyv[1], asi(Ev[1]));
        bk = (keyv[2] >> 25) & 63;
        ix = atomicAdd(&s_hist[(8 + p) * 64 + bk], 1);
        s_staS[ix] = make_int2(keyv[2], asi(Ev[2]));

        float acc = 0.f;
        #pragma unroll
        for (int k = 0; k < 8; ++k)
            acc += av[k].x * bv[k].x + av[k].y * bv[k].y
                 + av[k].z * bv[k].z + av[k].w * bv[k].w;
        acc += __shfl_xor(acc, 1);
        acc += __shfl_xor(acc, 2);
        acc += __shfl_xor(acc, 4);
        if (q == 0) s_eu[r] = acc;                  // 20*TEMP = 1.0
    }
    __syncthreads();

    // ---- P4: softmax over eu, kl, dotbase (wave 0) ----
    if (tid < 64) {
        float e  = s_eu[tid];
        float mx = e;
        #pragma unroll
        for (int m = 1; m < 64; m <<= 1) mx = fmaxf(mx, __shfl_xor(mx, m));
        float ex = __expf(e - mx);
        float z  = ex;
        #pragma unroll
        for (int m = 1; m < 64; m <<= 1) z += __shfl_xor(z, m);
        float pe = ex / z;
        s_peu[tid] = pe;
        float kls = pe * ((e - mx) - __logf(z));
        #pragma unroll
        for (int m = 1; m < 64; m <<= 1) kls += __shfl_xor(kls, m);
        if (tid == 0) s_kl = kls;
        // dotbase[g] = sum_s peu[s] * b2d[s,g]  (same wave; no barrier needed)
        int g = tid & 7, j = tid >> 3;
        float a = 0.f;
        #pragma unroll
        for (int k = 0; k < 8; ++k) {
            int s = 8 * j + k;
            a = fmaf(s_peu[s], s_b2d[s * TPd + g], a);
        }
        #pragma unroll
        for (int m = 8; m < 64; m <<= 1) a += __shfl_xor(a, m);
        if (tid < TPd) s_dotb[g] = a;
    }
    __syncthreads();

    // ---- P5: level-6 leaf sums (1 dyn + 1 sta job per thread) ----
    {
        const int bk = tid >> 3;                    // p = tid & 7
        int st = s_starts[p * 65 + bk], en = s_starts[p * 65 + bk + 1];
        float2 E2 = make_float2(0.f, 0.f), P2 = make_float2(0.f, 0.f);
        for (int i = st; i < en; ++i) {
            int2  q  = s_dynS[i];
            float e  = asf(q.y);
            float pe = s_peu[(q.x >> 1) & 63];
            if (q.x & 1) { E2.y += e; P2.y += pe; } else { E2.x += e; P2.x += pe; }
        }
        s_pyr[p * PYR_P + 62 + bk]         = E2;
        s_pyr[p * PYR_P + OFF_P + 62 + bk] = P2;
        st = s_starts[(8 + p) * 65 + bk]; en = s_starts[(8 + p) * 65 + bk + 1];
        float2 S2 = make_float2(0.f, 0.f);
        for (int i = st; i < en; ++i) {
            int2 q = s_staS[i];
            if (q.x & 1) S2.y += asf(q.y); else S2.x += asf(q.y);
        }
        s_pyr[p * PYR_P + OFF_S + 62 + bk] = S2;
    }

    // ---- P6: pyramid reduce, levels 5..1 ----
    for (int L = 5; L >= 1; --L) {
        __syncthreads();
        const int cnt = 24 << L;                    // 3 arrays x 8 p x 2^L
        const int cb  = (2 << L) - 2;
        const int pb  = (1 << L) - 2;
        for (int j = tid; j < cnt; j += 512) {
            int n  = j & ((1 << L) - 1);
            int g  = j >> L;
            int a  = g % 3;
            int pp = g / 3;
            int base = pp * PYR_P + a * 126;
            float2 c0 = s_pyr[base + cb + 2 * n];
            float2 c1 = s_pyr[base + cb + 2 * n + 1];
            s_pyr[base + pb + n] = make_float2(c0.x + c1.x, c0.y + c1.y);
        }
    }
    __syncthreads();

    // ---- P7: pair evaluation ----
    auto pair_eval = [&](int ac, int pp, float& outd, float& outs) {
        const float2* pyrp = s_pyr + pp * PYR_P;
        const int b0 = ac & 1;
        float sum, dot = 0.f, s2;
        {   // L1: e=16, cos=0, T=1
            int idx = ((ac >> 30) & 1) ^ 1;
            float2 dE = pyrp[idx], sE = pyrp[idx + OFF_S];
            sum = dE.x + dE.y;
            s2  = sE.x + sE.y;
        }
#define LVL(L, CD_, TDP_, TDM_, TSP_, TSM_) { \
        int idx = ((((ac >> (31 - (L))) & ((1 << (L)) - 1)) ^ 1) + ((1 << (L)) - 2)); \
        float2 dE = pyrp[idx]; float2 dP = pyrp[idx + OFF_P]; float2 sE = pyrp[idx + OFF_S]; \
        float Em = b0 ? dE.y : dE.x, En = b0 ? dE.x : dE.y; \
        float Pm = b0 ? dP.y : dP.x, Pn = b0 ? dP.x : dP.y; \
        float Sm = b0 ? sE.y : sE.x, Sn = b0 ? sE.x : sE.y; \
        sum = fmaf(TDP_, Em, fmaf(TDM_, En, sum)); \
        dot = fmaf(CD_, Pm - Pn, dot); \
        s2  = fmaf(TSP_, Sm, fmaf(TSM_, Sn, s2)); }
        LVL(2, 0.0112710550f, 1.00784308f, 0.99221794f, 1.16911840f, 0.85534531f)
        LVL(3, 0.0225421100f, 1.01574770f, 0.98449643f, 1.36683784f, 0.73161561f)
        LVL(4, 0.0338131650f, 1.02371431f, 0.97683501f, 1.59799517f, 0.62578409f)
        LVL(5, 0.0450842200f, 1.03174341f, 0.96923323f, 1.86824557f, 0.53526138f)
        LVL(6, 0.0563552750f, 1.03983561f, 0.96169061f, 2.18420029f, 0.45783352f)
#undef LVL
        const int bk = (ac >> 25) & 63;
        {   // dyn residual (same top-6 prefix): exact per-element
            int st = s_starts[pp * 65 + bk], en = s_starts[pp * 65 + bk + 1];
            for (int i = st; i < en; ++i) {
                int2  q  = s_dynS[i];
                int   y  = q.x ^ ac;
                float cc = cos15(y, ADYN);
                sum = fmaf(asf(q.y), exp2_fast(cc), sum);
                dot = fmaf(s_peu[(y >> 1) & 63], cc, dot);
            }
        }
        {   // sta residual
            int st = s_starts[(8 + pp) * 65 + bk], en = s_starts[(8 + pp) * 65 + bk + 1];
            for (int i = st; i < en; ++i) {
                int2 q = s_staS[i];
                s2 = fmaf(asf(q.y), exp2_fast(cos15(q.x ^ ac, ASTA)), s2);
            }
        }
        float b2t = __log2f(s_tarE[pp]);
        float cct = cos15(s_tarK[pp] ^ ac, ASTA);
        outd = s_kl + LN2 * (__log2f(sum) - (s_dotb[pp] + dot));
        outs = LN2 * (__log2f(s2) - (b2t + cct));
    };

    {
        float od, os;
        pair_eval(s_cnc[tid], p, od, os);
        out[(size_t)t * NC * TPd + tid]        = od;
        out[OUT1 + (size_t)t * NC * TPd + tid] = os;
        if (tid < 8) {  // tail pairs c = 64
            float od2, os2;
            pair_eval(s_cnc[512 + tid], tid, od2, os2);
            out[(size_t)t * NC * TPd + 512 + tid]        = od2;
            out[OUT1 + (size_t)t * NC * TPd + 512 + tid] = os2;
        }
    }
}

extern "C" void kernel_launch(void* const* d_in, const int* in_sizes, int n_in,
                              void* d_out, int out_size, void* d_ws, size_t ws_size,
                              hipStream_t stream) {
    (void)in_sizes; (void)n_in; (void)d_ws; (void)ws_size; (void)out_size;
    const int*   cur_tar = (const int*)  d_in[0];
    const int*   cnc_loc = (const int*)  d_in[1];
    const int*   sta_loc = (const int*)  d_in[2];
    const int*   ttn_loc = (const int*)  d_in[3];
    const int*   voc_loc = (const int*)  d_in[4];
    const float* sta_emb = (const float*)d_in[5];
    const float* ttn_emb = (const float*)d_in[6];
    // d_in[7] (voc_emb) intentionally unused: it only feeds eu_val[:,64:], discarded.
    critigraph_kernel<<<Tn, 512, 0, stream>>>(cur_tar, cnc_loc, sta_loc, ttn_loc,
                                              voc_loc, sta_emb, ttn_emb, (float*)d_out);
}